// Round 1
// baseline (782.940 us; speedup 1.0000x reference)
//
#include <hip/hip_runtime.h>
#include <cstdint>

// Problem constants
#define M_TOK 32768   // B*S
#define BERT  768
#define HID   512
#define LAT   128
#define NV    4096
#define NK    100
#define VOCAB 30522
#define NB    128     // batch B

typedef short short8 __attribute__((ext_vector_type(8)));
typedef float floatx4 __attribute__((ext_vector_type(4)));
typedef unsigned short u16x4 __attribute__((ext_vector_type(4)));

// ---- bf16 split helpers (RNE, manual bit ops: no API ambiguity) -----------
__device__ __forceinline__ unsigned short f2bf(float f) {
    unsigned u = __float_as_uint(f);
    unsigned r = (u + 0x7FFFu + ((u >> 16) & 1u)) >> 16;
    return (unsigned short)r;
}
__device__ __forceinline__ float bf2f(unsigned short h) {
    return __uint_as_float((unsigned)h << 16);
}

// ---- async global->LDS, 16B per lane --------------------------------------
__device__ __forceinline__ void async16(const void* g, void* l) {
    __builtin_amdgcn_global_load_lds(
        (const __attribute__((address_space(1))) unsigned int*)g,
        (__attribute__((address_space(3))) unsigned int*)l, 16, 0, 0);
}

// ---------------------------------------------------------------------------
// Weight split+transpose: W[K][N] f32 -> Wt limbs [NL=3][N][K] bf16.
// ---------------------------------------------------------------------------
__global__ __launch_bounds__(256) void wsplit(
    const float* __restrict__ W, unsigned short* __restrict__ Wt,
    int K, int N)
{
    int j = blockIdx.x * 256 + threadIdx.x;     // index over [N][K]
    int total = N * K;
    if (j >= total) return;
    int n = j / K, k = j - n * K;
    float v = W[(size_t)k * N + n];
    unsigned short h = f2bf(v);
    float r = v - bf2f(h);
    unsigned short m = f2bf(r);
    float r2 = r - bf2f(m);
    unsigned short l = f2bf(r2);
    Wt[j] = h;
    Wt[(size_t)total + j] = m;
    Wt[(size_t)2 * total + j] = l;
}

// ---------------------------------------------------------------------------
// A-presplit: A[M][K] f32 -> planes [3][M][K] bf16 (same RNE chain as the
// in-kernel split it replaces -> bit-identical limbs). BW-bound.
// ---------------------------------------------------------------------------
__global__ __launch_bounds__(256) void asplit(
    const float* __restrict__ A, unsigned short* __restrict__ P, int total)
{
    int j = (blockIdx.x * 256 + threadIdx.x) * 4;
    if (j >= total) return;
    float4 v4 = *(const float4*)(A + j);
    float vv[4] = {v4.x, v4.y, v4.z, v4.w};
    u16x4 h4, m4, l4;
#pragma unroll
    for (int e = 0; e < 4; ++e) {
        float v = vv[e];
        unsigned short h = f2bf(v);
        float r = v - bf2f(h);
        unsigned short m = f2bf(r);
        float r2 = r - bf2f(m);
        h4[e] = h; m4[e] = m; l4[e] = f2bf(r2);
    }
    *(u16x4*)(P + j) = h4;
    *(u16x4*)(P + (size_t)total + j) = m4;
    *(u16x4*)(P + (size_t)2 * total + j) = l4;
}

// ---------------------------------------------------------------------------
// Multi-limb bf16 MFMA GEMM, legacy 128x128 structure (kept for enc2/dec1).
// OUT=0: f32 C (+bias, opt ReLU). OUT=2: write 2 bf16 limb planes of the
// post-bias/relu value into C (cast) -- feeds gemm8p's A operand.
// ---------------------------------------------------------------------------
template<int NL, bool RELU, int OUT = 0>
__global__ __launch_bounds__(256) void gemm_mfma(
    const float* __restrict__ A, const unsigned short* __restrict__ Wt,
    const float* __restrict__ bias, float* __restrict__ C,
    int M, int N, int K)
{
    __shared__ unsigned short Ash[NL][128 * 32];
    __shared__ unsigned short Bsh[NL][128 * 32];

    const int tid  = threadIdx.x;
    const int lane = tid & 63;
    const int wave = tid >> 6;
    const int bm = blockIdx.y * 128;
    const int bn = blockIdx.x * 128;
    const int wm = (wave & 1) * 64;
    const int wn = (wave >> 1) * 64;

    const int ar = tid >> 3;          // 0..31
    const int ak = (tid & 7) * 4;     // 0,4,..28
    const int br = tid >> 2;          // 0..63
    const int bk = (tid & 3) * 8;     // 0,8,16,24

    floatx4 acc[4][4];
#pragma unroll
    for (int t = 0; t < 4; ++t)
#pragma unroll
        for (int u = 0; u < 4; ++u)
            acc[t][u] = (floatx4)0.0f;

    float4 av[4];
#pragma unroll
    for (int i = 0; i < 4; ++i)
        av[i] = *(const float4*)(A + (size_t)(bm + ar + 32 * i) * K + ak);

    for (int k0 = 0; k0 < K; k0 += 32) {
        u16x4 ah[NL][4];
#pragma unroll
        for (int i = 0; i < 4; ++i) {
            float vv[4] = {av[i].x, av[i].y, av[i].z, av[i].w};
#pragma unroll
            for (int e = 0; e < 4; ++e) {
                float v = vv[e];
                unsigned short h = f2bf(v);
                float r = v - bf2f(h);
                unsigned short m = f2bf(r);
                ah[0][i][e] = h;
                ah[1][i][e] = m;
                if (NL == 3) {
                    float r2 = r - bf2f(m);
                    ah[2][i][e] = f2bf(r2);
                }
            }
        }
        __syncthreads();
#pragma unroll
        for (int l = 0; l < NL; ++l) {
            const unsigned short* wp = Wt + (size_t)l * N * K;
#pragma unroll
            for (int i = 0; i < 2; ++i)
                async16(wp + (size_t)(bn + br + 64 * i) * K + k0 + bk,
                        &Bsh[l][i * 2048 + tid * 8]);
        }
#pragma unroll
        for (int l = 0; l < NL; ++l)
#pragma unroll
            for (int i = 0; i < 4; ++i)
                *(u16x4*)&Ash[l][(ar + 32 * i) * 32 + ak] = ah[l][i];
        if (k0 + 32 < K) {
#pragma unroll
            for (int i = 0; i < 4; ++i)
                av[i] = *(const float4*)(A + (size_t)(bm + ar + 32 * i) * K + k0 + 32 + ak);
        }
        __syncthreads();

        short8 af[NL][4];
#pragma unroll
        for (int l = 0; l < NL; ++l)
#pragma unroll
            for (int t = 0; t < 4; ++t)
                af[l][t] = *(const short8*)&Ash[l][(wm + t * 16 + (lane & 15)) * 32 + (lane >> 4) * 8];

#pragma unroll
        for (int bl = 0; bl < NL; ++bl) {
            short8 bf[4];
#pragma unroll
            for (int u = 0; u < 4; ++u)
                bf[u] = *(const short8*)&Bsh[bl][(wn + u * 16 + (lane & 15)) * 32 + (lane >> 4) * 8];
#pragma unroll
            for (int al = 0; al < NL; ++al) {
                if (al + bl >= NL) continue;
#pragma unroll
                for (int t = 0; t < 4; ++t)
#pragma unroll
                    for (int u = 0; u < 4; ++u)
                        acc[t][u] = __builtin_amdgcn_mfma_f32_16x16x32_bf16(
                            af[al][t], bf[u], acc[t][u], 0, 0, 0);
            }
        }
    }

    unsigned short* P0 = (unsigned short*)C;
    unsigned short* P1 = P0 + (size_t)M * N;
#pragma unroll
    for (int t = 0; t < 4; ++t) {
        int row0 = bm + wm + t * 16 + (lane >> 4) * 4;
#pragma unroll
        for (int u = 0; u < 4; ++u) {
            int col = bn + wn + u * 16 + (lane & 15);
            float b = bias[col];
#pragma unroll
            for (int r = 0; r < 4; ++r) {
                float v = acc[t][u][r] + b;
                if (RELU) v = fmaxf(v, 0.f);
                if (OUT == 0) {
                    C[(size_t)(row0 + r) * N + col] = v;
                } else {
                    unsigned short hh = f2bf(v);
                    unsigned short mm = f2bf(v - bf2f(hh));
                    P0[(size_t)(row0 + r) * N + col] = hh;
                    P1[(size_t)(row0 + r) * N + col] = mm;
                }
            }
        }
    }
}

// ---------------------------------------------------------------------------
// 256x256 / BK=64 double-buffered multi-limb GEMM (8-phase-style schedule):
// raw s_barrier + counted vmcnt(8) (never drains in steady state), counted
// lgkmcnt quadrant phases, setprio around MFMA clusters, XOR slot-swizzled
// LDS (inverse-swizzled global source + swizzled ds_read, rule 21).
// Limb-product sum linearized as K' = NP*K; chunk c -> (plane_a, plane_b, k)
// in EXACTLY the legacy kernel's per-k0 product order => per-fragment
// accumulation chains are bit-identical.
//   NP=6: (al,bl) = (0,0),(1,0),(2,0),(0,1),(1,1),(0,2)   [3-limb, ~f32-exact]
//   NP=3: (al,bl) = (0,0),(1,0),(0,1)                     [2-limb]
// 512 thr = 8 waves (2M x 4N), wave tile 128x64, acc 8x4 x floatx4.
// LDS 128 KiB -> 1 block/CU, 2 waves/SIMD (template-proven regime).
// ---------------------------------------------------------------------------
template<int NP, bool RELU>
__global__ __launch_bounds__(512, 2) void gemm8p(
    const unsigned short* __restrict__ Ap,   // [NLA][M][K] bf16 planes
    const unsigned short* __restrict__ Bp,   // [NLB][N][K] bf16 planes
    const float* __restrict__ bias, float* __restrict__ C,
    int M, int N, int K, int NT)             // NT = NP*K/64 (>= 2)
{
    __shared__ unsigned short As[2][256 * 64];   // 64 KiB
    __shared__ unsigned short Bs[2][256 * 64];   // 64 KiB

    const int tid  = threadIdx.x;
    const int lane = tid & 63;
    const int wid  = tid >> 6;
    const int wm   = (wid & 1) * 128;
    const int wn   = (wid >> 1) * 64;
    const int bm   = blockIdx.y * 256;
    const int bn   = blockIdx.x * 256;

    // swizzled read-side constants: row&7 == lane&7 for all fragment rows
    const int laneR = lane & 15;
    const int kgrp  = lane >> 4;
    const int swz   = lane & 7;
    const int slot0 = ((kgrp)     ^ swz) * 8;    // kk=0 slot (ushort offset)
    const int slot1 = ((4 + kgrp) ^ swz) * 8;    // kk=1 slot
    const int abase = (wm + laneR) * 64;
    const int bbase = (wn + laneR) * 64;

    floatx4 acc[8][4];
#pragma unroll
    for (int m = 0; m < 8; ++m)
#pragma unroll
        for (int n = 0; n < 4; ++n) acc[m][n] = (floatx4)0.0f;

    // stage one 64-wide k'-tile (A 32KB + B 32KB) = 8 global_load_lds / thread
    auto stage = [&](int b, int T) {
        int c0 = 2 * T, c1 = 2 * T + 1;
        int ki0, j0, ki1, j1, al0, bl0, al1, bl1;
        if (NP == 6) {
            ki0 = c0 / 6; j0 = c0 - ki0 * 6;
            ki1 = c1 / 6; j1 = c1 - ki1 * 6;
            al0 = j0 < 3 ? j0 : (j0 < 5 ? j0 - 3 : 0);
            bl0 = j0 < 3 ? 0  : (j0 < 5 ? 1 : 2);
            al1 = j1 < 3 ? j1 : (j1 < 5 ? j1 - 3 : 0);
            bl1 = j1 < 3 ? 0  : (j1 < 5 ? 1 : 2);
        } else {
            ki0 = c0 / 3; j0 = c0 - ki0 * 3;
            ki1 = c1 / 3; j1 = c1 - ki1 * 3;
            al0 = (j0 == 1); bl0 = (j0 == 2);
            al1 = (j1 == 1); bl1 = (j1 == 2);
        }
        const unsigned short* A0 = Ap + (size_t)al0 * M * K + ki0 * 32;
        const unsigned short* A1 = Ap + (size_t)al1 * M * K + ki1 * 32;
        const unsigned short* B0 = Bp + (size_t)bl0 * N * K + ki0 * 32;
        const unsigned short* B1 = Bp + (size_t)bl1 * N * K + ki1 * 32;
#pragma unroll
        for (int i = 0; i < 4; ++i) {
            int s   = i * 512 + tid;
            int row = s >> 3;
            int e0  = ((s & 7) ^ (row & 7)) * 8;   // inverse-swizzled source
            const unsigned short* src = ((e0 & 32) ? A1 : A0)
                                        + (size_t)(bm + row) * K + (e0 & 31);
            async16(src, &As[b][s * 8]);           // linear LDS dest
        }
#pragma unroll
        for (int i = 0; i < 4; ++i) {
            int s   = i * 512 + tid;
            int row = s >> 3;
            int e0  = ((s & 7) ^ (row & 7)) * 8;
            const unsigned short* src = ((e0 & 32) ? B1 : B0)
                                        + (size_t)(bn + row) * K + (e0 & 31);
            async16(src, &Bs[b][s * 8]);
        }
    };

    stage(0, 0);
    stage(1, 1);   // 16 loads in flight

    for (int t = 0; t < NT; ++t) {
        const int cb = t & 1;
        // wait THIS tile's 8 loads; next tile's 8 stay in flight (counted!)
        if (t + 1 < NT) asm volatile("s_waitcnt vmcnt(8)" ::: "memory");
        else            asm volatile("s_waitcnt vmcnt(0)" ::: "memory");
        __builtin_amdgcn_s_barrier();
        asm volatile("" ::: "memory");

        const unsigned short* Ab = &As[cb][0];
        const unsigned short* Bb = &Bs[cb][0];
        short8 a0[4][2], a1[4][2], b0f[2][2], b1f[2][2];
        // issue order (pinned): a0(8), b0(4), b1(4), a1(8) = 24 ds_read_b128
#pragma unroll
        for (int m = 0; m < 4; ++m) {
            a0[m][0] = *(const short8*)&Ab[abase + m * 1024 + slot0];
            a0[m][1] = *(const short8*)&Ab[abase + m * 1024 + slot1];
        }
        __builtin_amdgcn_sched_barrier(0);
#pragma unroll
        for (int n = 0; n < 2; ++n) {
            b0f[n][0] = *(const short8*)&Bb[bbase + n * 1024 + slot0];
            b0f[n][1] = *(const short8*)&Bb[bbase + n * 1024 + slot1];
        }
        __builtin_amdgcn_sched_barrier(0);
#pragma unroll
        for (int n = 0; n < 2; ++n) {
            b1f[n][0] = *(const short8*)&Bb[bbase + (2 + n) * 1024 + slot0];
            b1f[n][1] = *(const short8*)&Bb[bbase + (2 + n) * 1024 + slot1];
        }
        __builtin_amdgcn_sched_barrier(0);
#pragma unroll
        for (int m = 0; m < 4; ++m) {
            a1[m][0] = *(const short8*)&Ab[abase + (4 + m) * 1024 + slot0];
            a1[m][1] = *(const short8*)&Ab[abase + (4 + m) * 1024 + slot1];
        }

        // Q0: (mh0, nh0) -- needs a0+b0 (oldest 12)
        asm volatile("s_waitcnt lgkmcnt(12)" ::: "memory");
        __builtin_amdgcn_sched_barrier(0);
        __builtin_amdgcn_s_setprio(1);
#pragma unroll
        for (int m = 0; m < 4; ++m)
#pragma unroll
            for (int n = 0; n < 2; ++n)
#pragma unroll
                for (int kk = 0; kk < 2; ++kk)
                    acc[m][n] = __builtin_amdgcn_mfma_f32_16x16x32_bf16(
                        a0[m][kk], b0f[n][kk], acc[m][n], 0, 0, 0);
        __builtin_amdgcn_s_setprio(0);

        // Q1: (mh0, nh1) -- needs b1 (a1's 8 may stay outstanding)
        asm volatile("s_waitcnt lgkmcnt(8)" ::: "memory");
        __builtin_amdgcn_sched_barrier(0);
        __builtin_amdgcn_s_setprio(1);
#pragma unroll
        for (int m = 0; m < 4; ++m)
#pragma unroll
            for (int n = 0; n < 2; ++n)
#pragma unroll
                for (int kk = 0; kk < 2; ++kk)
                    acc[m][2 + n] = __builtin_amdgcn_mfma_f32_16x16x32_bf16(
                        a0[m][kk], b1f[n][kk], acc[m][2 + n], 0, 0, 0);
        __builtin_amdgcn_s_setprio(0);

        // all reads of buf cb done -> safe to restage it after barrier
        asm volatile("s_waitcnt lgkmcnt(0)" ::: "memory");
        __builtin_amdgcn_sched_barrier(0);
        asm volatile("" ::: "memory");
        __builtin_amdgcn_s_barrier();
        asm volatile("" ::: "memory");
        if (t + 2 < NT) stage(cb, t + 2);   // issue overlaps Q2+Q3 MFMA

        __builtin_amdgcn_s_setprio(1);
        // Q2: (mh1, nh1)
#pragma unroll
        for (int m = 0; m < 4; ++m)
#pragma unroll
            for (int n = 0; n < 2; ++n)
#pragma unroll
                for (int kk = 0; kk < 2; ++kk)
                    acc[4 + m][2 + n] = __builtin_amdgcn_mfma_f32_16x16x32_bf16(
                        a1[m][kk], b1f[n][kk], acc[4 + m][2 + n], 0, 0, 0);
        // Q3: (mh1, nh0)
#pragma unroll
        for (int m = 0; m < 4; ++m)
#pragma unroll
            for (int n = 0; n < 2; ++n)
#pragma unroll
                for (int kk = 0; kk < 2; ++kk)
                    acc[4 + m][n] = __builtin_amdgcn_mfma_f32_16x16x32_bf16(
                        a1[m][kk], b0f[n][kk], acc[4 + m][n], 0, 0, 0);
        __builtin_amdgcn_s_setprio(0);
    }

    // epilogue: D col=lane&15, row=(lane>>4)*4+reg  [m89/m91-verified]
#pragma unroll
    for (int mf = 0; mf < 8; ++mf) {
        int row0 = bm + wm + mf * 16 + (lane >> 4) * 4;
#pragma unroll
        for (int nf = 0; nf < 4; ++nf) {
            int col = bn + wn + nf * 16 + (lane & 15);
            float b = bias[col];
#pragma unroll
            for (int r = 0; r < 4; ++r) {
                float v = acc[mf][nf][r] + b;
                if (RELU) v = fmaxf(v, 0.f);
                C[(size_t)(row0 + r) * N + col] = v;
            }
        }
    }
}

// ---------------------------------------------------------------------------
// Row L2-normalize, rows of length 128. One wave (64 lanes) per row.
// ---------------------------------------------------------------------------
__global__ __launch_bounds__(64) void rownorm128(const float* __restrict__ in,
                                                 float* __restrict__ out)
{
    int row = blockIdx.x;
    int l = threadIdx.x;
    const float* p = in + (size_t)row * 128;
    float v0 = p[l], v1 = p[l + 64];
    float s = v0 * v0 + v1 * v1;
#pragma unroll
    for (int o = 32; o > 0; o >>= 1) s += __shfl_xor(s, o, 64);
    float inv = 1.0f / sqrtf(s);
    float* q = out + (size_t)row * 128;
    q[l] = v0 * inv;
    q[l + 64] = v1 * inv;
}

// ---------------------------------------------------------------------------
__global__ __launch_bounds__(128) void seg_scatter(
    const float* __restrict__ z, const int* __restrict__ ids,
    float* __restrict__ seg, float* __restrict__ freq)
{
    int row = blockIdx.x;
    int l = threadIdx.x;
    int id = ids[row];
    atomicAdd(&seg[(size_t)id * 128 + l], z[(size_t)row * 128 + l]);
    if (l == 0) atomicAdd(&freq[id], 1.0f);
}

// ---------------------------------------------------------------------------
__global__ __launch_bounds__(128) void avg_kernel(
    const float* __restrict__ seg, const float* __restrict__ freq,
    float* __restrict__ avg)
{
    int i = blockIdx.x;
    int l = threadIdx.x;
    float f = fmaxf(freq[i], 1.0f);
    avg[(size_t)i * 128 + l] = seg[(size_t)i * 128 + l] / f;
}

// ---------------------------------------------------------------------------
__global__ __launch_bounds__(128) void argmax_kernel(
    const float* __restrict__ avg, const float* __restrict__ cn,
    int* __restrict__ cids, float* __restrict__ cids_f)
{
    __shared__ float arow[128];
    __shared__ float lg[NK];
    int row = blockIdx.x;
    int t = threadIdx.x;
    arow[t] = avg[(size_t)row * 128 + t];
    __syncthreads();
    if (t < NK) {
        float d = 0.f;
        const float* c = cn + (size_t)t * 128;
#pragma unroll 8
        for (int i = 0; i < 128; ++i) d += arow[i] * c[i];
        lg[t] = d;
    }
    __syncthreads();
    if (t == 0) {
        float best = lg[0];
        int bi = 0;
        for (int k = 1; k < NK; ++k) {
            if (lg[k] > best) { best = lg[k]; bi = k; }
        }
        cids[row] = bi;
        cids_f[row] = (float)bi;
    }
}

// ---------------------------------------------------------------------------
__global__ __launch_bounds__(256) void build_masks(
    const float* __restrict__ bow, unsigned long long* __restrict__ masks,
    float* __restrict__ cnt)
{
    int j = blockIdx.x * 256 + threadIdx.x;
    if (j >= NV) return;
    unsigned long long m0 = 0, m1 = 0;
    for (int b = 0; b < 64; ++b)
        if (bow[(size_t)b * VOCAB + j] != 0.f) m0 |= 1ull << b;
    for (int b = 0; b < 64; ++b)
        if (bow[(size_t)(b + 64) * VOCAB + j] != 0.f) m1 |= 1ull << b;
    masks[2 * j] = m0;
    masks[2 * j + 1] = m1;
    cnt[j] = (float)(__popcll(m0) + __popcll(m1));
}

// ---------------------------------------------------------------------------
__global__ __launch_bounds__(256) void co_kernel(
    const unsigned long long* __restrict__ masks, const float* __restrict__ cnt,
    float* __restrict__ co)
{
    int j = blockIdx.x * 256 + threadIdx.x;
    unsigned long long m0 = masks[2 * j], m1 = masks[2 * j + 1];
    float cj = cnt[j];
    int ibase = blockIdx.y * 64;
    for (int ii = 0; ii < 64; ++ii) {
        int i = ibase + ii;
        unsigned long long a0 = masks[2 * i], a1 = masks[2 * i + 1];
        float ci = cnt[i];
        float c = (float)(__popcll(a0 & m0) + __popcll(a1 & m1));
        co[(size_t)i * NV + j] = (float)NB * c / (ci * cj);
    }
}

// ---------------------------------------------------------------------------
__global__ __launch_bounds__(128) void cluster_scan(
    const float* __restrict__ avg, const int* __restrict__ cids,
    const float* __restrict__ freq, const float* __restrict__ vw,
    const float* __restrict__ centers, const float* __restrict__ counts,
    float* __restrict__ out_centers)
{
    __shared__ int list[NV];
    __shared__ float coef[NV];
    __shared__ int tcnt[128];
    __shared__ int tot;
    __shared__ float Ptot;

    int k = blockIdx.x;
    int t = threadIdx.x;

    int base = t * (NV / 128);
    int c = 0;
    for (int s = 0; s < NV / 128; ++s) {
        int i = base + s;
        if (cids[i] == k && freq[i] > 0.f) c++;
    }
    tcnt[t] = c;
    __syncthreads();
    if (t == 0) {
        int run = 0;
        for (int x = 0; x < 128; ++x) { int v = tcnt[x]; tcnt[x] = run; run += v; }
        tot = run;
    }
    __syncthreads();
    int off = tcnt[t];
    for (int s = 0; s < NV / 128; ++s) {
        int i = base + s;
        if (cids[i] == k && freq[i] > 0.f) list[off++] = i;
    }
    __syncthreads();
    int m = tot;

    float c0 = counts[k];
    for (int j = t; j < m; j += 128)
        coef[j] = vw[list[j]] / (c0 + (float)(j + 1));
    __syncthreads();
    if (t == 0) {
        float suf = 1.f;
        for (int j = m - 1; j >= 0; --j) {
            float e = coef[j];
            coef[j] = e * suf;
            suf *= (1.f - e);
        }
        Ptot = suf;
    }
    __syncthreads();

    float accv = Ptot * centers[(size_t)k * 128 + t];
    for (int j = 0; j < m; ++j)
        accv += coef[j] * avg[(size_t)list[j] * 128 + t];
    out_centers[(size_t)k * 128 + t] = accv;
}

// ---------------------------------------------------------------------------
__global__ __launch_bounds__(64) void cn_norm(const float* __restrict__ centers,
                                              float* __restrict__ cn)
{
    int row = blockIdx.x;
    int l = threadIdx.x;
    const float* p = centers + (size_t)row * 128;
    float v0 = p[l], v1 = p[l + 64];
    float s = v0 * v0 + v1 * v1;
#pragma unroll
    for (int o = 32; o > 0; o >>= 1) s += __shfl_xor(s, o, 64);
    float inv = 1.0f / sqrtf(s);
    cn[(size_t)row * 128 + l] = v0 * inv;
    cn[(size_t)row * 128 + l + 64] = v1 * inv;
}

// ---------------------------------------------------------------------------
extern "C" void kernel_launch(void* const* d_in, const int* in_sizes, int n_in,
                              void* d_out, int out_size, void* d_ws, size_t ws_size,
                              hipStream_t stream)
{
    const int*   input_ids = (const int*)d_in[0];
    const float* token_embs = (const float*)d_in[3];
    const float* bow       = (const float*)d_in[4];
    const float* enc_w1    = (const float*)d_in[5];
    const float* enc_b1    = (const float*)d_in[6];
    const float* enc_w2    = (const float*)d_in[7];
    const float* enc_b2    = (const float*)d_in[8];
    const float* dec_w1    = (const float*)d_in[9];
    const float* dec_b1    = (const float*)d_in[10];
    const float* dec_w2    = (const float*)d_in[11];
    const float* dec_b2    = (const float*)d_in[12];
    const float* centers   = (const float*)d_in[13];
    const float* counts    = (const float*)d_in[14];
    const float* vocab_w   = (const float*)d_in[15];

    float* out = (float*)d_out;
    const size_t OFF_CO  = 0;                       // 4096*4096
    const size_t OFF_REC = 16777216;                // 32768*768
    const size_t OFF_AVG = OFF_REC + 25165824;      // 4096*128
    const size_t OFF_CID = OFF_AVG + 524288;        // 4096
    const size_t OFF_NC  = OFF_CID + 4096;          // 100*128

    // workspace layout
    float* h    = (float*)d_ws;                     // 32768*512 f32 (later: h2 limb planes)
    float* z    = h + (size_t)M_TOK * HID;          // 32768*128
    float* seg  = z + (size_t)M_TOK * LAT;          // 4096*128
    float* freq = seg + (size_t)NV * LAT;           // 4096
    float* cn   = freq + NV;                        // 100*128
    float* cntv = cn + (size_t)NK * LAT;            // 4096
    int*   cids = (int*)(cntv + NV);                // 4096
    unsigned long long* masks = (unsigned long long*)(cids + NV); // 4096*2
    unsigned short* wt1 = (unsigned short*)(masks + 2 * NV);      // 3*512*768
    unsigned short* wt2 = wt1 + (size_t)3 * HID * BERT;           // 3*128*512
    unsigned short* wt3 = wt2 + (size_t)3 * LAT * HID;            // 3*512*128
    unsigned short* wt4 = wt3 + (size_t)3 * HID * LAT;            // 3*768*512

    // token_embs limb planes (151 MB) live in the out-buffer's co+rec region
    // (167.8 MB). Consumed by enc1 BEFORE co_kernel/dec2 overwrite that
    // region later in the (serial) stream.
    unsigned short* a1p = (unsigned short*)out;

    // zero the atomic targets
    hipMemsetAsync(seg, 0, (size_t)(NV * LAT + NV) * sizeof(float), stream);

    // weight split+transpose (bf16 limbs, [N][K])
    wsplit<<<(BERT * HID + 255) / 256, 256, 0, stream>>>(enc_w1, wt1, BERT, HID);
    wsplit<<<(HID * LAT + 255) / 256, 256, 0, stream>>>(enc_w2, wt2, HID, LAT);
    wsplit<<<(LAT * HID + 255) / 256, 256, 0, stream>>>(dec_w1, wt3, LAT, HID);
    wsplit<<<(HID * BERT + 255) / 256, 256, 0, stream>>>(dec_w2, wt4, HID, BERT);

    // A-presplit for enc1 (bit-identical RNE limbs)
    asplit<<<(M_TOK * BERT / 4 + 255) / 256, 256, 0, stream>>>(
        token_embs, a1p, M_TOK * BERT);

    // encoder GEMM1: 8-phase 256x256, K' = 6*768 = 4608 -> h f32 (RELU)
    gemm8p<6, true><<<dim3(HID / 256, M_TOK / 256), 512, 0, stream>>>(
        a1p, wt1, enc_b1, h, M_TOK, HID, BERT, 6 * BERT / 64);

    // encoder GEMM2 (legacy structure; grid.x=1 so no redundant split)
    gemm_mfma<3, false><<<dim3(LAT / 128, M_TOK / 128), 256, 0, stream>>>(
        h, wt2, enc_b2, z, M_TOK, LAT, HID);
    rownorm128<<<M_TOK, 64, 0, stream>>>(z, z);

    // decoder GEMM1 (legacy): writes h2 as 2 bf16 limb planes into h buffer
    // (same 64 MB footprint; limbs == dec2's former in-kernel split of f32)
    gemm_mfma<2, true, 2><<<dim3(HID / 128, M_TOK / 128), 256, 0, stream>>>(
        z, wt3, dec_b1, h, M_TOK, HID, LAT);

    // decoder GEMM2: 8-phase 256x256, K' = 3*512 = 1536 -> rec f32
    gemm8p<3, false><<<dim3(BERT / 256, M_TOK / 256), 512, 0, stream>>>(
        (const unsigned short*)h, wt4, dec_b2, out + OFF_REC,
        M_TOK, BERT, HID, 3 * HID / 64);

    // segment mean
    seg_scatter<<<M_TOK, 128, 0, stream>>>(z, input_ids, seg, freq);
    avg_kernel<<<NV, 128, 0, stream>>>(seg, freq, out + OFF_AVG);

    // cluster assignment
    cn_norm<<<NK, 64, 0, stream>>>(centers, cn);
    argmax_kernel<<<NV, 128, 0, stream>>>(out + OFF_AVG, cn, cids, out + OFF_CID);

    // co-occurrence matrix (overwrites a1p region -- after enc1, safe)
    build_masks<<<NV / 256, 256, 0, stream>>>(bow, masks, cntv);
    co_kernel<<<dim3(NV / 256, NV / 64), 256, 0, stream>>>(masks, cntv, out + OFF_CO);

    // online center update (closed form)
    cluster_scan<<<NK, 128, 0, stream>>>(out + OFF_AVG, cids, freq, vocab_w,
                                         centers, counts, out + OFF_NC);
}